// Round 1
// baseline (106440.625 us; speedup 1.0000x reference)
//
#include <hip/hip_runtime.h>
#include <math.h>

#define B_   64
#define S_   512
#define IN_  512
#define H_   1024
#define NBLK 256
#define NTHR 512

// ---- static device scratch (avoids reliance on ws_size) ----
__device__ float g_xT[S_ * IN_ * B_];      // [s][k][b]  67 MB
__device__ float g_h0T[H_ * B_];           // [k][b]
__device__ float g_hT[2][H_ * B_];         // [k][b] double buffer
__device__ float g_hhatT[H_ * B_];         // [k][b]
__device__ float g_zprojT[H_ * B_];        // [j][b]  (includes b_lin)
__device__ unsigned g_bar[2 * S_];         // barrier slots, zeroed each launch

// ---------------- prologue 1: transpose inputs [B][S][IN] -> xT [S][IN][B] ----------------
__global__ void pre_transpose_x(const float* __restrict__ in) {
    __shared__ float lds[64][65];
    int s  = blockIdx.x >> 3;
    int k0 = (blockIdx.x & 7) << 6;
    int tid = threadIdx.x;
    int kk = tid & 63, bq = tid >> 6;
    for (int b = bq; b < 64; b += 4)
        lds[kk][b] = in[((size_t)b * S_ + s) * IN_ + k0 + kk];
    __syncthreads();
    int bb = tid & 63, kq = tid >> 6;
    for (int k = kq; k < 64; k += 4)
        g_xT[((size_t)s * IN_ + k0 + k) * B_ + bb] = lds[k][bb];
}

// ---------------- prologue 2: z_projT, h0T, zero barriers ----------------
__global__ void pre_misc(const float* __restrict__ z, const float* __restrict__ Wlin,
                         const float* __restrict__ blin, const float* __restrict__ h0) {
    __shared__ float zT[128][65];
    int j = blockIdx.x;      // 0..1023
    int b = threadIdx.x;     // 0..63
    for (int i = 0; i < 128; ++i) {
        int idx = b + (i << 6);
        zT[idx & 127][idx >> 7] = z[idx];
    }
    __syncthreads();
    float acc = blin[j];
    const float* w = Wlin + (size_t)j * (H_ + 128) + H_;
    for (int k = 0; k < 128; ++k)
        acc = fmaf(zT[k][b], w[k], acc);
    g_zprojT[j * 64 + b] = acc;
    g_h0T[j * 64 + b]    = h0[(size_t)b * H_ + j];
    if (j == 0)
        for (int i = b; i < 2 * S_; i += 64) g_bar[i] = 0;
}

// ---------------- grid barrier (device scope, cross-XCD safe) ----------------
__device__ __forceinline__ void grid_barrier(int slot) {
    __syncthreads();
    __threadfence();   // release: publish our global stores device-wide
    if (threadIdx.x == 0) {
        __hip_atomic_fetch_add(&g_bar[slot], 1u, __ATOMIC_RELAXED, __HIP_MEMORY_SCOPE_AGENT);
        while (__hip_atomic_load(&g_bar[slot], __ATOMIC_ACQUIRE, __HIP_MEMORY_SCOPE_AGENT) < NBLK)
            __builtin_amdgcn_s_sleep(2);
    }
    __syncthreads();
    __threadfence();   // acquire for all threads: drop stale cached lines
}

// ---------------- micro GEMM: 64 rows x 4 cols, weights in LDS ----------------
// AT: [K][64] (global, transposed activations); wl: LDS rows, given pitch.
// thread map: tr=tid&15 (4 rows each), tc=(tid>>4)&3 (col), kq=tid>>6 (K/8 chunk)
__device__ __forceinline__ void micro4(const float* __restrict__ AT,
                                       const float* __restrict__ wl, int pitch,
                                       int K, int tid, float* __restrict__ red) {
    int tr = tid & 15, tc = (tid >> 4) & 3, kq = tid >> 6;
    int kchunk = K >> 3;
    int k0 = kq * kchunk;
    const float* wp = wl + tc * pitch + k0;
    const float* ap = AT + (size_t)k0 * B_ + (tr << 2);
    float4 acc = {0.f, 0.f, 0.f, 0.f};
    for (int k = 0; k < kchunk; k += 4) {
        float4 w4 = *(const float4*)(wp + k);
        float4 a0 = *(const float4*)(ap + (size_t)(k + 0) * B_);
        float4 a1 = *(const float4*)(ap + (size_t)(k + 1) * B_);
        float4 a2 = *(const float4*)(ap + (size_t)(k + 2) * B_);
        float4 a3 = *(const float4*)(ap + (size_t)(k + 3) * B_);
        acc.x = fmaf(w4.x, a0.x, acc.x); acc.x = fmaf(w4.y, a1.x, acc.x);
        acc.x = fmaf(w4.z, a2.x, acc.x); acc.x = fmaf(w4.w, a3.x, acc.x);
        acc.y = fmaf(w4.x, a0.y, acc.y); acc.y = fmaf(w4.y, a1.y, acc.y);
        acc.y = fmaf(w4.z, a2.y, acc.y); acc.y = fmaf(w4.w, a3.y, acc.y);
        acc.z = fmaf(w4.x, a0.z, acc.z); acc.z = fmaf(w4.y, a1.z, acc.z);
        acc.z = fmaf(w4.z, a2.z, acc.z); acc.z = fmaf(w4.w, a3.z, acc.z);
        acc.w = fmaf(w4.x, a0.w, acc.w); acc.w = fmaf(w4.y, a1.w, acc.w);
        acc.w = fmaf(w4.z, a2.w, acc.w); acc.w = fmaf(w4.w, a3.w, acc.w);
    }
    float* rp = red + (((kq << 2) | tc) << 6) + (tr << 2);
    *(float4*)rp = acc;
}

// ---------------- persistent recurrence kernel ----------------
// 256 blocks x 512 threads; block owns output cols j = 4*blk .. +3 (and the
// matching gate-column triples). Weights for those columns live in LDS.
__launch_bounds__(NTHR)
__global__ void skipgru_persist(const float* __restrict__ Wlin, const float* __restrict__ Wih,
                                const float* __restrict__ bih,  const float* __restrict__ Whh,
                                const float* __restrict__ bhh,  float* __restrict__ out) {
    // LDS: weight slabs padded (+4 floats) to avoid bank conflicts, + tiles
    __shared__ float whh_l[12 * 1028];   // 49.3 KB  rows {q*H+jbase+i}
    __shared__ float wih_l[12 * 516];    // 24.8 KB
    __shared__ float wlin_l[4 * 1028];   // 16.4 KB  (first 1024 cols of W_lin rows)
    __shared__ float red[8 * 4 * 64];    // 8 KB k-reduce scratch
    __shared__ float hhat[4 * 64];
    __shared__ float gi_t[3 * 4 * 64];
    __shared__ float gh_t[3 * 4 * 64];

    const int tid = threadIdx.x;
    const int jbase = blockIdx.x << 2;
    const int c = tid >> 6, r = tid & 63;   // for reduce/gate threads (tid<256)

    // stage weights
    for (int idx = tid; idx < 12 * 1024; idx += NTHR) {
        int row = idx >> 10, k = idx & 1023;
        int col = ((row >> 2) << 10) + jbase + (row & 3);
        whh_l[row * 1028 + k] = Whh[(size_t)col * H_ + k];
    }
    for (int idx = tid; idx < 12 * 512; idx += NTHR) {
        int row = idx >> 9, k = idx & 511;
        int col = ((row >> 2) << 10) + jbase + (row & 3);
        wih_l[row * 516 + k] = Wih[(size_t)col * IN_ + k];
    }
    for (int idx = tid; idx < 4 * 1024; idx += NTHR) {
        int row = idx >> 10, k = idx & 1023;
        wlin_l[row * 1028 + k] = Wlin[(size_t)(jbase + row) * (H_ + 128) + k];
    }
    __syncthreads();

    for (int t = 0; t < S_; ++t) {
        const float* hsrc = (t == 0) ? g_h0T : g_hT[t & 1];

        // ---- phase A: h_hat (4 cols) ----
        micro4(hsrc, wlin_l, 1028, H_, tid, red);
        __syncthreads();
        if (tid < 256) {
            float s = g_zprojT[(jbase + c) * 64 + r];
            #pragma unroll
            for (int kq = 0; kq < 8; ++kq) s += red[(((kq << 2) | c) << 6) | r];
            hhat[(c << 6) | r] = s;
            g_hhatT[(jbase + c) * 64 + r] = s;
        }
        __syncthreads();

        // ---- phase A: gi (12 cols = 3 gate groups x 4) ----
        const float* xT = g_xT + (size_t)t * IN_ * B_;
        for (int cg = 0; cg < 3; ++cg) {
            micro4(xT, wih_l + cg * 4 * 516, 516, IN_, tid, red);
            __syncthreads();
            if (tid < 256) {
                float s = bih[cg * H_ + jbase + c];
                #pragma unroll
                for (int kq = 0; kq < 8; ++kq) s += red[(((kq << 2) | c) << 6) | r];
                gi_t[cg * 256 + (c << 6) + r] = s;
            }
            __syncthreads();
        }

        grid_barrier(2 * t);               // all h_hat published

        // ---- phase B: gh (12 cols) ----
        for (int cg = 0; cg < 3; ++cg) {
            micro4(g_hhatT, whh_l + cg * 4 * 1028, 1028, H_, tid, red);
            __syncthreads();
            if (tid < 256) {
                float s = bhh[cg * H_ + jbase + c];
                #pragma unroll
                for (int kq = 0; kq < 8; ++kq) s += red[(((kq << 2) | c) << 6) | r];
                gh_t[cg * 256 + (c << 6) + r] = s;
            }
            __syncthreads();
        }

        // ---- gates + writeback ----
        if (tid < 256) {
            int j = jbase + c;
            int o = (c << 6) | r;
            float ir = gi_t[o], iz = gi_t[256 + o], inn = gi_t[512 + o];
            float hr = gh_t[o], hz = gh_t[256 + o], hnn = gh_t[512 + o];
            float hh = hhat[o];
            float rg = 1.f / (1.f + expf(-(ir + hr)));
            float ug = 1.f / (1.f + expf(-(iz + hz)));
            float ng = tanhf(inn + rg * hnn);
            float v  = (1.f - ug) * ng + ug * hh;
            g_hT[(t + 1) & 1][j * 64 + r] = v;
            out[((size_t)r * S_ + t) * H_ + j] = v;           // outs[b][t][j]
            if (t == S_ - 1)
                out[(size_t)B_ * S_ * H_ + (size_t)r * H_ + j] = v;  // hT
        }
        grid_barrier(2 * t + 1);           // h_new published, h_hat consumed
    }
}

extern "C" void kernel_launch(void* const* d_in, const int* in_sizes, int n_in,
                              void* d_out, int out_size, void* d_ws, size_t ws_size,
                              hipStream_t stream) {
    const float* inputs = (const float*)d_in[0];
    const float* h0     = (const float*)d_in[1];
    const float* z      = (const float*)d_in[2];
    const float* Wlin   = (const float*)d_in[3];
    const float* blin   = (const float*)d_in[4];
    const float* Wih    = (const float*)d_in[5];
    const float* bih    = (const float*)d_in[6];
    const float* Whh    = (const float*)d_in[7];
    const float* bhh    = (const float*)d_in[8];
    float* out = (float*)d_out;

    hipLaunchKernelGGL(pre_transpose_x, dim3(S_ * 8), dim3(256), 0, stream, inputs);
    hipLaunchKernelGGL(pre_misc, dim3(H_), dim3(64), 0, stream, z, Wlin, blin, h0);
    hipLaunchKernelGGL(skipgru_persist, dim3(NBLK), dim3(NTHR), 0, stream,
                       Wlin, Wih, bih, Whh, bhh, out);
}

// Round 5
// 82879.852 us; speedup vs baseline: 1.2843x; 1.2843x over previous
//
#include <hip/hip_runtime.h>
#include <math.h>

#define B_   64
#define S_   512
#define IN_  512
#define H_   1024
#define WLK_ (H_ + 128)
#define NBLK 256
#define NTHR 512

// ---- static device scratch ----
__device__ float g_xT[(size_t)S_ * IN_ * B_];   // [s][k][b]
__device__ float g_h0T[H_ * B_];                // [k][b]
__device__ float g_hT[2][H_ * B_];              // [k][b]
__device__ float g_hhatT[H_ * B_];              // [j][b]
__device__ float g_zprojT[H_ * B_];             // [j][b] includes b_lin
__device__ unsigned g_bar[2 * S_];

// ---------------- prologue 1: transpose inputs [B][S][IN] -> xT [S][IN][B] ----
__global__ void pre_transpose_x(const float* __restrict__ in) {
    __shared__ float lds[64][65];
    int s  = blockIdx.x >> 3;
    int k0 = (blockIdx.x & 7) << 6;
    int tid = threadIdx.x;
    int kk = tid & 63, bq = tid >> 6;
    for (int b = bq; b < 64; b += 4)
        lds[kk][b] = in[((size_t)b * S_ + s) * IN_ + k0 + kk];
    __syncthreads();
    int bb = tid & 63, kq = tid >> 6;
    for (int k = kq; k < 64; k += 4)
        g_xT[((size_t)s * IN_ + k0 + k) * B_ + bb] = lds[k][bb];
}

// ---------------- prologue 2: z_projT (incl b_lin), h0T, zero barriers ------
__global__ void pre_misc(const float* __restrict__ z, const float* __restrict__ Wlin,
                         const float* __restrict__ blin, const float* __restrict__ h0) {
    __shared__ float zT[128][65];
    int j = blockIdx.x;      // 0..1023
    int b = threadIdx.x;     // 0..63
    for (int i = 0; i < 128; ++i) {
        int idx = b + (i << 6);
        zT[idx & 127][idx >> 7] = z[idx];
    }
    __syncthreads();
    float acc = blin[j];
    const float* w = Wlin + (size_t)j * WLK_ + H_;
    for (int k = 0; k < 128; ++k)
        acc = fmaf(zT[k][b], w[k], acc);
    g_zprojT[j * 64 + b] = acc;
    g_h0T[j * 64 + b]    = h0[(size_t)b * H_ + j];
    if (j == 0)
        for (int i = b; i < 2 * S_; i += 64) g_bar[i] = 0;
}

#define F4(AC, WS) AC.x=fmaf(WS,a.x,AC.x); AC.y=fmaf(WS,a.y,AC.y); AC.z=fmaf(WS,a.z,AC.z); AC.w=fmaf(WS,a.w,AC.w);

// 12-col GEMM over K (512 or 1024): dst[c*64+b] = bias_l[c] + sum_k wl[k][c]*src[k][b]
// Thread map: bq=tid&15 (b=4bq..+3), kq=tid>>4 (k=kq+32i). Contains internal sync.
// Caller must ensure `red` is not being read when entering, and sync before
// reusing `red` afterwards.
__device__ __forceinline__ void gemm12(const float* __restrict__ src,
                                       const float* wl, int K,
                                       const float* bias_l, float* dst,
                                       float* red, int tid) {
    const int bq = tid & 15, kq = tid >> 4;
    const int wv = tid >> 6, ln = tid & 63;
    const float* ap = src + (kq << 6) + (bq << 2);
    const float* wp = wl + kq * 12;
    float4 acc[12];
    #pragma unroll
    for (int c = 0; c < 12; ++c) acc[c] = make_float4(0.f, 0.f, 0.f, 0.f);
    const int iters = K >> 5;
    #pragma unroll 4
    for (int i = 0; i < iters; ++i) {
        float4 a  = *(const float4*)ap;  ap += 32 * 64;
        float4 w0 = *(const float4*)(wp + 0);
        float4 w1 = *(const float4*)(wp + 4);
        float4 w2 = *(const float4*)(wp + 8);  wp += 32 * 12;
        F4(acc[0],w0.x) F4(acc[1],w0.y) F4(acc[2],w0.z)  F4(acc[3],w0.w)
        F4(acc[4],w1.x) F4(acc[5],w1.y) F4(acc[6],w1.z)  F4(acc[7],w1.w)
        F4(acc[8],w2.x) F4(acc[9],w2.y) F4(acc[10],w2.z) F4(acc[11],w2.w)
    }
    #pragma unroll
    for (int c = 0; c < 12; ++c) {
        float4 v = acc[c];
        v.x += __shfl_xor(v.x,16); v.y += __shfl_xor(v.y,16);
        v.z += __shfl_xor(v.z,16); v.w += __shfl_xor(v.w,16);
        v.x += __shfl_xor(v.x,32); v.y += __shfl_xor(v.y,32);
        v.z += __shfl_xor(v.z,32); v.w += __shfl_xor(v.w,32);
        if (ln < 16) *(float4*)&red[(wv * 12 + c) * 64 + (ln << 2)] = v;
    }
    __syncthreads();
    for (int o = tid; o < 768; o += NTHR) {
        int c = o >> 6, b = o & 63;
        float s = bias_l[c];
        #pragma unroll
        for (int w = 0; w < 8; ++w) s += red[(w * 12 + c) * 64 + b];
        dst[o] = s;
    }
}

// ---------------- persistent recurrence kernel ------------------------------
// 256 blocks x 512 threads; block owns hidden cols j = 4*blk..+3.
// Reference-faithful 2-phase step: P1 h_hat (4 cols) | barrier A |
// P2 gh (12 cols over h_hat) + gates | barrier B.  gi(t+1) hidden under A.
__launch_bounds__(NTHR, 1)
__global__ void skipgru_2ph(const float* __restrict__ Wlin, const float* __restrict__ Wih,
                            const float* __restrict__ bih,  const float* __restrict__ Whh,
                            const float* __restrict__ bhh,  float* __restrict__ out) {
    __shared__ float wA[H_ * 4];        // 16 KB [k][c<4]   Wlin_h rows jb..+3
    __shared__ float wB[H_ * 12];       // 48 KB [k][c<12]  Whh rows g*H+jb+i
    __shared__ float wX[IN_ * 12];      // 24 KB [k][c<12]  Wih rows
    __shared__ float red[8 * 12 * 64];  // 24 KB
    __shared__ float gh_l[12 * 64];
    __shared__ float gi_a[12 * 64];
    __shared__ float gi_b[12 * 64];
    __shared__ float hh_l[4 * 64];
    __shared__ float zp_l[4 * 64];
    __shared__ float bhh_l[12];
    __shared__ float bih_l[12];

    const int tid = threadIdx.x;
    const int jb  = blockIdx.x << 2;
    const int bq  = tid & 15;
    const int kq  = tid >> 4;
    const int wv  = tid >> 6, ln = tid & 63;

    // ---- stage weights (once) ----
    for (int c = 0; c < 4; ++c) {
        const float* src = Wlin + (size_t)(jb + c) * WLK_;
        for (int k = tid; k < H_; k += NTHR) wA[k * 4 + c] = src[k];
    }
    for (int c = 0; c < 12; ++c) {
        const float* src = Whh + (size_t)((c >> 2) * H_ + jb + (c & 3)) * H_;
        for (int k = tid; k < H_; k += NTHR) wB[k * 12 + c] = src[k];
    }
    for (int c = 0; c < 12; ++c) {
        const float* src = Wih + (size_t)((c >> 2) * H_ + jb + (c & 3)) * IN_;
        for (int k = tid; k < IN_; k += NTHR) wX[k * 12 + c] = src[k];
    }
    if (tid < 256) zp_l[tid] = g_zprojT[(jb + (tid >> 6)) * 64 + (tid & 63)];
    if (tid < 12) {
        bhh_l[tid] = bhh[(tid >> 2) * H_ + jb + (tid & 3)];
        bih_l[tid] = bih[(tid >> 2) * H_ + jb + (tid & 3)];
    }
    __syncthreads();

    // ---- gi(0) -> gi_a ----
    gemm12(g_xT, wX, IN_, bih_l, gi_a, red, tid);
    __syncthreads();

    for (int t = 0; t < S_; ++t) {
        const float* hs = (t == 0) ? g_h0T : g_hT[t & 1];
        const float* gi_cur = (t & 1) ? gi_b : gi_a;
        float*       gi_nxt = (t & 1) ? gi_a : gi_b;

        // ---- P1: h_hat, 4 cols, K=1024 ----
        {
            const float* ap = hs + (kq << 6) + (bq << 2);
            const float* wp = wA + kq * 4;
            float4 acc[4];
            #pragma unroll
            for (int c = 0; c < 4; ++c) acc[c] = make_float4(0.f, 0.f, 0.f, 0.f);
            #pragma unroll 4
            for (int i = 0; i < 32; ++i) {
                float4 a = *(const float4*)ap;  ap += 32 * 64;
                float4 w = *(const float4*)wp;  wp += 32 * 4;
                F4(acc[0],w.x) F4(acc[1],w.y) F4(acc[2],w.z) F4(acc[3],w.w)
            }
            #pragma unroll
            for (int c = 0; c < 4; ++c) {
                float4 v = acc[c];
                v.x += __shfl_xor(v.x,16); v.y += __shfl_xor(v.y,16);
                v.z += __shfl_xor(v.z,16); v.w += __shfl_xor(v.w,16);
                v.x += __shfl_xor(v.x,32); v.y += __shfl_xor(v.y,32);
                v.z += __shfl_xor(v.z,32); v.w += __shfl_xor(v.w,32);
                if (ln < 16) *(float4*)&red[(wv * 4 + c) * 64 + (ln << 2)] = v;
            }
        }
        __syncthreads();
        if (tid < 256) {
            int c = tid >> 6, b = tid & 63;
            float s = zp_l[tid];
            #pragma unroll
            for (int w = 0; w < 8; ++w) s += red[(w * 4 + c) * 64 + b];
            hh_l[tid] = s;
            g_hhatT[(jb + c) * 64 + b] = s;
        }
        __syncthreads();

        // ---- arrive A (release h_hat) ----
        __threadfence();
        if (tid == 0)
            __hip_atomic_fetch_add(&g_bar[2 * t], 1u, __ATOMIC_RELAXED, __HIP_MEMORY_SCOPE_AGENT);

        // ---- gi(t+1), hidden under barrier A ----
        if (t + 1 < S_)
            gemm12(g_xT + (size_t)(t + 1) * IN_ * B_, wX, IN_, bih_l, gi_nxt, red, tid);

        // ---- wait A ----
        if (tid == 0) {
            while (__hip_atomic_load(&g_bar[2 * t], __ATOMIC_RELAXED, __HIP_MEMORY_SCOPE_AGENT) < NBLK)
                __builtin_amdgcn_s_sleep(2);
            (void)__hip_atomic_load(&g_bar[2 * t], __ATOMIC_ACQUIRE, __HIP_MEMORY_SCOPE_AGENT);
        }
        __syncthreads();
        __threadfence();

        // ---- P2: gh, 12 cols over h_hat, K=1024 ----
        gemm12(g_hhatT, wB, H_, bhh_l, gh_l, red, tid);
        __syncthreads();

        // ---- gates + writeback (threads 0..255) ----
        if (tid < 256) {
            int cc = tid >> 6, b = tid & 63;
            float hh = hh_l[tid];
            float hr = gh_l[cc * 64 + b];
            float hz = gh_l[(4 + cc) * 64 + b];
            float hn = gh_l[(8 + cc) * 64 + b];
            float ir = gi_cur[cc * 64 + b];
            float iz = gi_cur[(4 + cc) * 64 + b];
            float in_ = gi_cur[(8 + cc) * 64 + b];
            float r = 1.f / (1.f + expf(-(ir + hr)));
            float u = 1.f / (1.f + expf(-(iz + hz)));
            float n = tanhf(in_ + r * hn);
            float v = (1.f - u) * n + u * hh;
            int j = jb + cc;
            g_hT[(t + 1) & 1][j * 64 + b] = v;
            out[((size_t)b * S_ + t) * H_ + j] = v;
            if (t == S_ - 1)
                out[(size_t)B_ * S_ * H_ + (size_t)b * H_ + j] = v;
        }
        __syncthreads();

        // ---- arrive B (release h_new) + wait B ----
        __threadfence();
        if (tid == 0) {
            __hip_atomic_fetch_add(&g_bar[2 * t + 1], 1u, __ATOMIC_RELAXED, __HIP_MEMORY_SCOPE_AGENT);
            while (__hip_atomic_load(&g_bar[2 * t + 1], __ATOMIC_RELAXED, __HIP_MEMORY_SCOPE_AGENT) < NBLK)
                __builtin_amdgcn_s_sleep(2);
            (void)__hip_atomic_load(&g_bar[2 * t + 1], __ATOMIC_ACQUIRE, __HIP_MEMORY_SCOPE_AGENT);
        }
        __syncthreads();
        __threadfence();
    }
}

extern "C" void kernel_launch(void* const* d_in, const int* in_sizes, int n_in,
                              void* d_out, int out_size, void* d_ws, size_t ws_size,
                              hipStream_t stream) {
    const float* inputs = (const float*)d_in[0];
    const float* h0     = (const float*)d_in[1];
    const float* z      = (const float*)d_in[2];
    const float* Wlin   = (const float*)d_in[3];
    const float* blin   = (const float*)d_in[4];
    const float* Wih    = (const float*)d_in[5];
    const float* bih    = (const float*)d_in[6];
    const float* Whh    = (const float*)d_in[7];
    const float* bhh    = (const float*)d_in[8];
    float* out = (float*)d_out;

    hipLaunchKernelGGL(pre_transpose_x, dim3(S_ * 8), dim3(256), 0, stream, inputs);
    hipLaunchKernelGGL(pre_misc, dim3(H_), dim3(64), 0, stream, z, Wlin, blin, h0);
    hipLaunchKernelGGL(skipgru_2ph, dim3(NBLK), dim3(NTHR), 0, stream,
                       Wlin, Wih, bih, Whh, bhh, out);
}

// Round 7
// 11486.497 us; speedup vs baseline: 9.2666x; 7.2154x over previous
//
#include <hip/hip_runtime.h>
#include <math.h>

#define B_   64
#define S_   512
#define IN_  512
#define H_   1024
#define WLK_ (H_ + 128)
#define NBLK 256
#define NTHR 512

typedef unsigned long long ull;

// ---- static device scratch ----
__device__ float g_xT[(size_t)S_ * IN_ * B_];   // [s][k][b]
__device__ float g_h0T[H_ * B_];                // [k][b]
__device__ float g_hT[2][H_ * B_];              // [k][b]
__device__ float g_hhatT[H_ * B_];              // [j][b]
__device__ float g_zprojT[H_ * B_];             // [j][b] includes b_lin
__device__ unsigned g_bar[2 * S_][256];         // 8 live counters/slot, 128B apart

// coherent 4-float load/2-float store: relaxed agent-scope atomics execute at
// the device coherence point — per-access coherence, NO L2-walk fences.
__device__ __forceinline__ float4 coh_load4(const float* p) {
    const ull* q = (const ull*)p;
    ull u0 = __hip_atomic_load(q,     __ATOMIC_RELAXED, __HIP_MEMORY_SCOPE_AGENT);
    ull u1 = __hip_atomic_load(q + 1, __ATOMIC_RELAXED, __HIP_MEMORY_SCOPE_AGENT);
    union { ull u; float2 f; } a, b;
    a.u = u0; b.u = u1;
    return make_float4(a.f.x, a.f.y, b.f.x, b.f.y);
}
__device__ __forceinline__ void coh_store2(float* p, float x, float y) {
    union { float2 f; ull u; } v; v.f = make_float2(x, y);
    __hip_atomic_store((ull*)p, v.u, __ATOMIC_RELAXED, __HIP_MEMORY_SCOPE_AGENT);
}

// ---------------- prologue 1: transpose inputs [B][S][IN] -> xT [S][IN][B] ----
__global__ void pre_transpose_x(const float* __restrict__ in) {
    __shared__ float lds[64][65];
    int s  = blockIdx.x >> 3;
    int k0 = (blockIdx.x & 7) << 6;
    int tid = threadIdx.x;
    int kk = tid & 63, bq = tid >> 6;
    for (int b = bq; b < 64; b += 4)
        lds[kk][b] = in[((size_t)b * S_ + s) * IN_ + k0 + kk];
    __syncthreads();
    int bb = tid & 63, kq = tid >> 6;
    for (int k = kq; k < 64; k += 4)
        g_xT[((size_t)s * IN_ + k0 + k) * B_ + bb] = lds[k][bb];
}

// ---------------- prologue 2: z_projT (incl b_lin), h0T, zero barriers ------
__global__ void pre_misc(const float* __restrict__ z, const float* __restrict__ Wlin,
                         const float* __restrict__ blin, const float* __restrict__ h0) {
    __shared__ float zT[128][65];
    int j = blockIdx.x;      // 0..1023
    int b = threadIdx.x;     // 0..63
    for (int i = 0; i < 128; ++i) {
        int idx = b + (i << 6);
        zT[idx & 127][idx >> 7] = z[idx];
    }
    __syncthreads();
    float acc = blin[j];
    const float* w = Wlin + (size_t)j * WLK_ + H_;
    for (int k = 0; k < 128; ++k)
        acc = fmaf(zT[k][b], w[k], acc);
    g_zprojT[j * 64 + b] = acc;
    g_h0T[j * 64 + b]    = h0[(size_t)b * H_ + j];
    // zero barrier row j: 256 uints per row, 1024 rows == gridDim (FIX: was
    // j<<9 stride over a 256-uint row -> 1MB overflow past g_bar -> abort)
    for (int i = b; i < 256; i += 64)
        g_bar[j][i] = 0;
}

#define F4(AC, WS) AC.x=fmaf(WS,a.x,AC.x); AC.y=fmaf(WS,a.y,AC.y); AC.z=fmaf(WS,a.z,AC.z); AC.w=fmaf(WS,a.w,AC.w);

// 12-col GEMM over K: dst[c*64+b] = bias_l[c] + sum_k wl[k][c]*src[k][b]
// COH: load src via agent-scope atomics (cross-block coherent data).
template<bool COH>
__device__ __forceinline__ void gemm12(const float* __restrict__ src,
                                       const float* wl, int K,
                                       const float* bias_l, float* dst,
                                       float* red, int tid) {
    const int bq = tid & 15, kq = tid >> 4;
    const int wv = tid >> 6, ln = tid & 63;
    const float* ap = src + (kq << 6) + (bq << 2);
    const float* wp = wl + kq * 12;
    float4 acc[12];
    #pragma unroll
    for (int c = 0; c < 12; ++c) acc[c] = make_float4(0.f, 0.f, 0.f, 0.f);
    const int iters = K >> 5;
    #pragma unroll 4
    for (int i = 0; i < iters; ++i) {
        float4 a = COH ? coh_load4(ap) : *(const float4*)ap;
        ap += 32 * 64;
        float4 w0 = *(const float4*)(wp + 0);
        float4 w1 = *(const float4*)(wp + 4);
        float4 w2 = *(const float4*)(wp + 8);  wp += 32 * 12;
        F4(acc[0],w0.x) F4(acc[1],w0.y) F4(acc[2],w0.z)  F4(acc[3],w0.w)
        F4(acc[4],w1.x) F4(acc[5],w1.y) F4(acc[6],w1.z)  F4(acc[7],w1.w)
        F4(acc[8],w2.x) F4(acc[9],w2.y) F4(acc[10],w2.z) F4(acc[11],w2.w)
    }
    #pragma unroll
    for (int c = 0; c < 12; ++c) {
        float4 v = acc[c];
        v.x += __shfl_xor(v.x,16); v.y += __shfl_xor(v.y,16);
        v.z += __shfl_xor(v.z,16); v.w += __shfl_xor(v.w,16);
        v.x += __shfl_xor(v.x,32); v.y += __shfl_xor(v.y,32);
        v.z += __shfl_xor(v.z,32); v.w += __shfl_xor(v.w,32);
        if (ln < 16) *(float4*)&red[(wv * 12 + c) * 64 + (ln << 2)] = v;
    }
    __syncthreads();
    for (int o = tid; o < 768; o += NTHR) {
        int c = o >> 6, b = o & 63;
        float s = bias_l[c];
        #pragma unroll
        for (int w = 0; w < 8; ++w) s += red[(w * 12 + c) * 64 + b];
        dst[o] = s;
    }
}

// ---------------- persistent recurrence kernel ------------------------------
// 256 blocks x 512 threads; block owns hidden cols j = 4*blk..+3.
// 2-phase step: P1 h_hat | barrier A | P2 gh + gates | barrier B.
// gi(t+1) hidden under barrier A. NO agent fences anywhere: cross-block data
// moves via relaxed agent-scope atomics (coherent at device point);
// __syncthreads' vmcnt(0) drain orders data stores before the arrive-add.
__launch_bounds__(NTHR, 1)
__global__ void skipgru_2ph(const float* __restrict__ Wlin, const float* __restrict__ Wih,
                            const float* __restrict__ bih,  const float* __restrict__ Whh,
                            const float* __restrict__ bhh,  float* __restrict__ out) {
    __shared__ float wA[H_ * 4];        // 16 KB [k][c<4]   Wlin_h rows jb..+3
    __shared__ float wB[H_ * 12];       // 48 KB [k][c<12]  Whh rows g*H+jb+i
    __shared__ float wX[IN_ * 12];      // 24 KB [k][c<12]  Wih rows
    __shared__ float red[8 * 12 * 64];  // 24 KB
    __shared__ float gh_l[12 * 64];
    __shared__ float gi_a[12 * 64];
    __shared__ float gi_b[12 * 64];
    __shared__ float hh_l[4 * 64];
    __shared__ float hn_l[4 * 64];
    __shared__ float zp_l[4 * 64];
    __shared__ float bhh_l[12];
    __shared__ float bih_l[12];

    const int tid = threadIdx.x;
    const int jb  = blockIdx.x << 2;
    const int bq  = tid & 15;
    const int kq  = tid >> 4;
    const int wv  = tid >> 6, ln = tid & 63;
    const int barlane = (blockIdx.x & 7) << 5;   // 8 counters, 128 B apart

    // ---- stage weights (once) ----
    for (int c = 0; c < 4; ++c) {
        const float* src = Wlin + (size_t)(jb + c) * WLK_;
        for (int k = tid; k < H_; k += NTHR) wA[k * 4 + c] = src[k];
    }
    for (int c = 0; c < 12; ++c) {
        const float* src = Whh + (size_t)((c >> 2) * H_ + jb + (c & 3)) * H_;
        for (int k = tid; k < H_; k += NTHR) wB[k * 12 + c] = src[k];
    }
    for (int c = 0; c < 12; ++c) {
        const float* src = Wih + (size_t)((c >> 2) * H_ + jb + (c & 3)) * IN_;
        for (int k = tid; k < IN_; k += NTHR) wX[k * 12 + c] = src[k];
    }
    if (tid < 256) zp_l[tid] = g_zprojT[(jb + (tid >> 6)) * 64 + (tid & 63)];
    if (tid < 12) {
        bhh_l[tid] = bhh[(tid >> 2) * H_ + jb + (tid & 3)];
        bih_l[tid] = bih[(tid >> 2) * H_ + jb + (tid & 3)];
    }
    __syncthreads();

    // ---- gi(0) -> gi_a ----
    gemm12<false>(g_xT, wX, IN_, bih_l, gi_a, red, tid);
    __syncthreads();

    for (int t = 0; t < S_; ++t) {
        const float* hs = (t == 0) ? g_h0T : g_hT[t & 1];
        const float* gi_cur = (t & 1) ? gi_b : gi_a;
        float*       gi_nxt = (t & 1) ? gi_a : gi_b;

        // ---- P1: h_hat, 4 cols, K=1024 (coherent h loads) ----
        {
            const float* ap = hs + (kq << 6) + (bq << 2);
            const float* wp = wA + kq * 4;
            float4 acc[4];
            #pragma unroll
            for (int c = 0; c < 4; ++c) acc[c] = make_float4(0.f, 0.f, 0.f, 0.f);
            #pragma unroll 4
            for (int i = 0; i < 32; ++i) {
                float4 a = coh_load4(ap);  ap += 32 * 64;
                float4 w = *(const float4*)wp;  wp += 32 * 4;
                F4(acc[0],w.x) F4(acc[1],w.y) F4(acc[2],w.z) F4(acc[3],w.w)
            }
            #pragma unroll
            for (int c = 0; c < 4; ++c) {
                float4 v = acc[c];
                v.x += __shfl_xor(v.x,16); v.y += __shfl_xor(v.y,16);
                v.z += __shfl_xor(v.z,16); v.w += __shfl_xor(v.w,16);
                v.x += __shfl_xor(v.x,32); v.y += __shfl_xor(v.y,32);
                v.z += __shfl_xor(v.z,32); v.w += __shfl_xor(v.w,32);
                if (ln < 16) *(float4*)&red[(wv * 4 + c) * 64 + (ln << 2)] = v;
            }
        }
        __syncthreads();
        if (tid < 256) {
            int c = tid >> 6, b = tid & 63;
            float s = zp_l[tid];
            #pragma unroll
            for (int w = 0; w < 8; ++w) s += red[(w * 4 + c) * 64 + b];
            hh_l[tid] = s;
        }
        __syncthreads();
        if (tid < 128) {
            int c = tid >> 5, pb = (tid & 31) << 1;
            coh_store2(&g_hhatT[(jb + c) * 64 + pb], hh_l[(c << 6) + pb], hh_l[(c << 6) + pb + 1]);
        }
        __syncthreads();   // vmcnt(0) drain: h_hat stores complete before arrive

        // ---- arrive A ----
        if (tid == 0)
            __hip_atomic_fetch_add(&g_bar[2 * t][barlane], 1u, __ATOMIC_RELAXED, __HIP_MEMORY_SCOPE_AGENT);

        // ---- gi(t+1), hidden under barrier A ----
        if (t + 1 < S_)
            gemm12<false>(g_xT + (size_t)(t + 1) * IN_ * B_, wX, IN_, bih_l, gi_nxt, red, tid);

        // ---- wait A ----
        if (tid == 0) {
            unsigned s;
            do {
                s = 0;
                #pragma unroll
                for (int i = 0; i < 8; ++i)
                    s += __hip_atomic_load(&g_bar[2 * t][i << 5], __ATOMIC_RELAXED, __HIP_MEMORY_SCOPE_AGENT);
                if (s < NBLK) __builtin_amdgcn_s_sleep(2);
            } while (s < NBLK);
        }
        __syncthreads();

        // ---- P2: gh, 12 cols over h_hat, K=1024 (coherent) ----
        gemm12<true>(g_hhatT, wB, H_, bhh_l, gh_l, red, tid);
        __syncthreads();

        // ---- gates + writeback (threads 0..255) ----
        if (tid < 256) {
            int cc = tid >> 6, b = tid & 63;
            float hh = hh_l[tid];
            float hr = gh_l[cc * 64 + b];
            float hz = gh_l[(4 + cc) * 64 + b];
            float hn = gh_l[(8 + cc) * 64 + b];
            float ir = gi_cur[cc * 64 + b];
            float iz = gi_cur[(4 + cc) * 64 + b];
            float in_ = gi_cur[(8 + cc) * 64 + b];
            float r = 1.f / (1.f + expf(-(ir + hr)));
            float u = 1.f / (1.f + expf(-(iz + hz)));
            float n = tanhf(in_ + r * hn);
            float v = (1.f - u) * n + u * hh;
            hn_l[tid] = v;
            int j = jb + cc;
            out[((size_t)b * S_ + t) * H_ + j] = v;
            if (t == S_ - 1)
                out[(size_t)B_ * S_ * H_ + (size_t)b * H_ + j] = v;
        }
        __syncthreads();
        if (tid < 128) {
            int c = tid >> 5, pb = (tid & 31) << 1;
            coh_store2(&g_hT[(t + 1) & 1][(jb + c) * 64 + pb], hn_l[(c << 6) + pb], hn_l[(c << 6) + pb + 1]);
        }
        __syncthreads();   // vmcnt(0) drain: h stores complete before arrive

        // ---- arrive B + wait B ----
        if (tid == 0) {
            __hip_atomic_fetch_add(&g_bar[2 * t + 1][barlane], 1u, __ATOMIC_RELAXED, __HIP_MEMORY_SCOPE_AGENT);
            unsigned s;
            do {
                s = 0;
                #pragma unroll
                for (int i = 0; i < 8; ++i)
                    s += __hip_atomic_load(&g_bar[2 * t + 1][i << 5], __ATOMIC_RELAXED, __HIP_MEMORY_SCOPE_AGENT);
                if (s < NBLK) __builtin_amdgcn_s_sleep(2);
            } while (s < NBLK);
        }
        __syncthreads();
    }
}

extern "C" void kernel_launch(void* const* d_in, const int* in_sizes, int n_in,
                              void* d_out, int out_size, void* d_ws, size_t ws_size,
                              hipStream_t stream) {
    const float* inputs = (const float*)d_in[0];
    const float* h0     = (const float*)d_in[1];
    const float* z      = (const float*)d_in[2];
    const float* Wlin   = (const float*)d_in[3];
    const float* blin   = (const float*)d_in[4];
    const float* Wih    = (const float*)d_in[5];
    const float* bih    = (const float*)d_in[6];
    const float* Whh    = (const float*)d_in[7];
    const float* bhh    = (const float*)d_in[8];
    float* out = (float*)d_out;

    hipLaunchKernelGGL(pre_transpose_x, dim3(S_ * 8), dim3(256), 0, stream, inputs);
    hipLaunchKernelGGL(pre_misc, dim3(H_), dim3(64), 0, stream, z, Wlin, blin, h0);
    hipLaunchKernelGGL(skipgru_2ph, dim3(NBLK), dim3(NTHR), 0, stream,
                       Wlin, Wih, bih, Whh, bhh, out);
}